// Round 2
// baseline (650.221 us; speedup 1.0000x reference)
//
#include <hip/hip_runtime.h>
#include <hip/hip_bf16.h>
#include <math.h>

using bf16 = __hip_bfloat16;
typedef __attribute__((ext_vector_type(8))) short short8;
typedef __attribute__((ext_vector_type(4))) float f32x4;

static constexpr int B_ = 4, C_ = 512, L_ = 4096, M_ = 16384;
static constexpr size_t MB = 1ull << 20;

__device__ __forceinline__ float b2f(bf16 v){ return __bfloat162float(v); }
__device__ __forceinline__ bf16  f2b(float v){ return __float2bfloat16(v); }

// ---------------- weight transpose fp32 -> bf16 (+ zero pad rows of Wt) ----
// W: K x N (row major, fp32). Wt: Npad x K (bf16), rows >= N are zero.
__global__ __launch_bounds__(256) void transpose_pad(const float* __restrict__ W,
    bf16* __restrict__ Wt, int K, int N, int Npad)
{
  __shared__ float tile[32][33];
  int k0 = blockIdx.x * 32, n0 = blockIdx.y * 32;
  int tx = threadIdx.x, ty = threadIdx.y;
  #pragma unroll
  for (int i = 0; i < 32; i += 8) {
    int k = k0 + ty + i, n = n0 + tx;
    tile[ty + i][tx] = (n < N) ? W[(size_t)k * N + n] : 0.f;
  }
  __syncthreads();
  #pragma unroll
  for (int i = 0; i < 32; i += 8) {
    int n = n0 + ty + i, k = k0 + tx;
    Wt[(size_t)n * K + k] = f2b(tile[tx][ty + i]);
  }
}

__global__ void pad_bias64(const float* __restrict__ b, float* __restrict__ bp){
  int i = threadIdx.x;           // 128 threads
  bp[i] = (i < 64) ? b[i] : 0.f;
}

// ---------------- GroupNorm stats (sum, sumsq per (b,g)) ----------------
__global__ __launch_bounds__(256) void gn_partial(const float* __restrict__ x,
                                                  float* __restrict__ stats)
{
  int bg = blockIdx.x >> 4;          // 0..31  (b*8+g)
  int sc = blockIdx.x & 15;          // 16-way split of the 262144-elem group
  size_t base = (size_t)bg * 262144 + (size_t)sc * 16384;
  int tid = threadIdx.x;
  float s = 0.f, s2 = 0.f;
  #pragma unroll
  for (int i = 0; i < 8; i++) {
    size_t o = base + ((size_t)i * 256 + tid) * 8;
    float4 a = *reinterpret_cast<const float4*>(&x[o]);
    float4 b = *reinterpret_cast<const float4*>(&x[o + 4]);
    s  += a.x + a.y + a.z + a.w + b.x + b.y + b.z + b.w;
    s2 += a.x*a.x + a.y*a.y + a.z*a.z + a.w*a.w
        + b.x*b.x + b.y*b.y + b.z*b.z + b.w*b.w;
  }
  #pragma unroll
  for (int o = 32; o; o >>= 1) { s += __shfl_xor(s, o, 64); s2 += __shfl_xor(s2, o, 64); }
  __shared__ float ls[4], ls2[4];
  int wave = tid >> 6, lane = tid & 63;
  if (lane == 0) { ls[wave] = s; ls2[wave] = s2; }
  __syncthreads();
  if (tid == 0) {
    atomicAdd(&stats[bg * 2 + 0], ls[0] + ls[1] + ls[2] + ls[3]);
    atomicAdd(&stats[bg * 2 + 1], ls2[0] + ls2[1] + ls2[2] + ls2[3]);
  }
}

// ---------------- GN apply + transpose (B,C,L) -> (B*L, C) bf16 ----------
__global__ __launch_bounds__(256) void gn_apply_t(const float* __restrict__ x,
    const float* __restrict__ stats, const float* __restrict__ gg,
    const float* __restrict__ gb, bf16* __restrict__ xnt)
{
  __shared__ float tile[32][33];
  int b = blockIdx.z, c0 = blockIdx.y * 32, l0 = blockIdx.x * 32;
  int tx = threadIdx.x, ty = threadIdx.y;
  #pragma unroll
  for (int i = 0; i < 32; i += 8) {
    int c = c0 + ty + i, l = l0 + tx;
    int grp = b * 8 + (c >> 6);
    float sum = stats[grp * 2], ss = stats[grp * 2 + 1];
    float mu = sum * (1.f / 262144.f);
    float inv = rsqrtf(ss * (1.f / 262144.f) - mu * mu + 1e-5f);
    float v = x[((size_t)b * 512 + c) * 4096 + l];
    tile[ty + i][tx] = (v - mu) * inv * gg[c] + gb[c];
  }
  __syncthreads();
  #pragma unroll
  for (int i = 0; i < 32; i += 8) {
    int l = l0 + ty + i, c = c0 + tx;
    xnt[((size_t)b * 4096 + l) * 512 + c] = f2b(tile[tx][ty + i]);
  }
}

// ---------------- LayerNorm over C=512: fp32 in, bf16 out, 1 wave/row -----
__global__ __launch_bounds__(256) void layernorm_k(const float* __restrict__ X,
    const float* __restrict__ g, const float* __restrict__ b, bf16* __restrict__ Y)
{
  int row = blockIdx.x * 4 + (threadIdx.x >> 6);
  int lane = threadIdx.x & 63;
  const float* xr = X + (size_t)row * 512 + lane * 8;
  float4 a = *reinterpret_cast<const float4*>(xr);
  float4 c = *reinterpret_cast<const float4*>(xr + 4);
  float v[8] = {a.x, a.y, a.z, a.w, c.x, c.y, c.z, c.w};
  float s = 0.f, s2 = 0.f;
  #pragma unroll
  for (int i = 0; i < 8; i++) { s += v[i]; s2 += v[i] * v[i]; }
  #pragma unroll
  for (int o = 32; o; o >>= 1) { s += __shfl_xor(s, o, 64); s2 += __shfl_xor(s2, o, 64); }
  float mu = s * (1.f / 512.f);
  float inv = rsqrtf(s2 * (1.f / 512.f) - mu * mu + 1e-5f);
  float4 g0 = *reinterpret_cast<const float4*>(&g[lane * 8]);
  float4 g1 = *reinterpret_cast<const float4*>(&g[lane * 8 + 4]);
  float4 b0 = *reinterpret_cast<const float4*>(&b[lane * 8]);
  float4 b1 = *reinterpret_cast<const float4*>(&b[lane * 8 + 4]);
  float gv[8] = {g0.x, g0.y, g0.z, g0.w, g1.x, g1.y, g1.z, g1.w};
  float bv[8] = {b0.x, b0.y, b0.z, b0.w, b1.x, b1.y, b1.z, b1.w};
  bf16 outv[8];
  #pragma unroll
  for (int i = 0; i < 8; i++) outv[i] = f2b((v[i] - mu) * inv * gv[i] + bv[i]);
  *reinterpret_cast<uint4*>(Y + (size_t)row * 512 + lane * 8) =
      *reinterpret_cast<const uint4*>(outv);
}

// ---------------- MFMA GEMM:  C[M,N] = A[M,K] * Bt[N,K]^T + bias (+epi) ----
// EPI: 0 none | 1 += res[idx] | 2 out = res[idx]*gelu(acc+bias)
// EPI 3: out[(b*512+n)*4096+l] = acc+bias+res[same], b=m>>12, l=m&4095 (fp32)
template<typename TOUT, typename TRES, int EPI>
__global__ __launch_bounds__(256) void gemm_bt(const bf16* __restrict__ A,
    const bf16* __restrict__ Bt, const float* __restrict__ bias,
    const TRES* __restrict__ res, TOUT* __restrict__ Cv, int M, int N, int K)
{
  __shared__ alignas(16) bf16 As[128][40];
  __shared__ alignas(16) bf16 Bs[128][40];
  const int tid = threadIdx.x;
  const int m0 = blockIdx.y * 128;
  const int n0 = blockIdx.x * 128;
  const int lane = tid & 63;
  const int wave = tid >> 6;
  const int wm = (wave >> 1) * 64;
  const int wn = (wave & 1) * 64;
  const int fr = lane & 15;
  const int fq = lane >> 4;

  f32x4 acc[4][4];
  #pragma unroll
  for (int i = 0; i < 4; i++)
    #pragma unroll
    for (int j = 0; j < 4; j++) acc[i][j] = (f32x4){0.f, 0.f, 0.f, 0.f};

  for (int kt = 0; kt < K; kt += 32) {
    __syncthreads();
    #pragma unroll
    for (int i = 0; i < 2; i++) {
      int seg = tid + i * 256;          // 512 segments: 128 rows x 4 x 16B
      int r = seg >> 2, sc = seg & 3;
      *reinterpret_cast<uint4*>(&As[r][sc * 8]) =
        *reinterpret_cast<const uint4*>(&A[(size_t)(m0 + r) * K + kt + sc * 8]);
      *reinterpret_cast<uint4*>(&Bs[r][sc * 8]) =
        *reinterpret_cast<const uint4*>(&Bt[(size_t)(n0 + r) * K + kt + sc * 8]);
    }
    __syncthreads();
    short8 af[4], bfv[4];
    #pragma unroll
    for (int mi = 0; mi < 4; mi++)
      af[mi] = *reinterpret_cast<const short8*>(&As[wm + mi * 16 + fr][fq * 8]);
    #pragma unroll
    for (int ni = 0; ni < 4; ni++)
      bfv[ni] = *reinterpret_cast<const short8*>(&Bs[wn + ni * 16 + fr][fq * 8]);
    #pragma unroll
    for (int mi = 0; mi < 4; mi++)
      #pragma unroll
      for (int ni = 0; ni < 4; ni++)
        acc[mi][ni] = __builtin_amdgcn_mfma_f32_16x16x32_bf16(af[mi], bfv[ni],
                                                              acc[mi][ni], 0, 0, 0);
  }

  // epilogue: C/D layout col = lane&15, row = (lane>>4)*4 + reg
  #pragma unroll
  for (int ni = 0; ni < 4; ni++) {
    int n = n0 + wn + ni * 16 + fr;
    float bv = bias[n];
    #pragma unroll
    for (int mi = 0; mi < 4; mi++) {
      int mbase = m0 + wm + mi * 16 + fq * 4;
      if (EPI == 3) {
        int b = mbase >> 12, l = mbase & 4095;
        size_t o = ((size_t)(b * 512 + n) << 12) + l;
        float4 xr = *reinterpret_cast<const float4*>(&((const float*)res)[o]);
        float4 vv;
        vv.x = acc[mi][ni][0] + bv + xr.x;
        vv.y = acc[mi][ni][1] + bv + xr.y;
        vv.z = acc[mi][ni][2] + bv + xr.z;
        vv.w = acc[mi][ni][3] + bv + xr.w;
        *reinterpret_cast<float4*>(&((float*)Cv)[o]) = vv;
      } else {
        #pragma unroll
        for (int r = 0; r < 4; r++) {
          size_t idx = (size_t)(mbase + r) * N + n;
          float v = acc[mi][ni][r] + bv;
          if (EPI == 1) {
            float rv;
            if constexpr (sizeof(TRES) == 2) rv = b2f(((const bf16*)res)[idx]);
            else                             rv = ((const float*)res)[idx];
            v += rv;
          }
          if (EPI == 2) {
            float a = b2f(((const bf16*)res)[idx]);
            v = a * (0.5f * v * (1.f + erff(v * 0.70710678118654752f)));
          }
          if constexpr (sizeof(TOUT) == 2) ((bf16*)Cv)[idx] = f2b(v);
          else                             ((float*)Cv)[idx] = v;
        }
      }
    }
  }
}

// ---------------- MSDA: degenerate deformable attention (Hl=L, Wl=1) ------
__global__ __launch_bounds__(256) void msda_k(const float* __restrict__ offb,
    const float* __restrict__ awl, const bf16* __restrict__ v2,
    bf16* __restrict__ outp)
{
  int unit = blockIdx.x * 4 + (threadIdx.x >> 6);  // (b*L+l)*8 + h
  int lane = threadIdx.x & 63;
  int m = unit >> 3;
  int h = unit & 7;
  int b = m >> 12;                                  // L = 4096
  const float* lg = &awl[(size_t)m * 128 + h * 8];
  float w[8], mx = -1e30f;
  #pragma unroll
  for (int p = 0; p < 8; p++) { w[p] = lg[p]; mx = fmaxf(mx, w[p]); }
  float sum = 0.f;
  #pragma unroll
  for (int p = 0; p < 8; p++) { w[p] = expf(w[p] - mx); sum += w[p]; }
  float rs = 1.f / sum;
  const float* op = &offb[(size_t)m * 128 + h * 16];
  size_t vbase = ((size_t)b * 4096) * 512 + h * 64 + lane;
  float acc = 0.f;
  #pragma unroll
  for (int p = 0; p < 8; p++) {
    float ox = op[p * 2 + 0], oy = op[p * 2 + 1];
    float gx = 2.f * (0.5f + ox) - 1.f;
    float px = ((gx + 1.f) * 1.f - 1.f) * 0.5f;              // = ox, mirrors ref fp ops
    float gy = 2.f * (0.5f + oy * (1.f / 4096.f)) - 1.f;
    float py = ((gy + 1.f) * 4096.f - 1.f) * 0.5f;           // = oy + 2047.5
    float x0 = floorf(px), y0 = floorf(py);
    float lx = px - x0, ly = py - y0;
    int xi = (int)x0;
    int yi = (int)y0;
    float wx = (xi == 0) ? (1.f - lx) : ((xi == -1) ? lx : 0.f);
    if (wx != 0.f) {                         // wave-uniform branch
      float s = 0.f;
      if (yi >= 0 && yi < 4096)  s += (1.f - ly) * b2f(v2[vbase + (size_t)yi * 512]);
      if (yi >= -1 && yi < 4095) s += ly * b2f(v2[vbase + (size_t)(yi + 1) * 512]);
      acc += w[p] * rs * wx * s;
    }
  }
  outp[(size_t)m * 512 + h * 64 + lane] = f2b(acc);
}

// =========================================================================
extern "C" void kernel_launch(void* const* d_in, const int* in_sizes, int n_in,
                              void* d_out, int out_size, void* d_ws, size_t ws_size,
                              hipStream_t stream)
{
  if (n_in < 27) return;
  const float* x       = (const float*)d_in[0];
  const float* gn_g    = (const float*)d_in[1];
  const float* gn_b    = (const float*)d_in[2];
  const float* pin_w   = (const float*)d_in[3];
  const float* pin_b   = (const float*)d_in[4];
  const float* ln1_g   = (const float*)d_in[5];
  const float* ln1_b   = (const float*)d_in[6];
  const float* vproj_w = (const float*)d_in[7];
  const float* vproj_b = (const float*)d_in[8];
  const float* mvp_w   = (const float*)d_in[9];
  const float* mvp_b   = (const float*)d_in[10];
  const float* soff_w  = (const float*)d_in[11];
  const float* soff_b  = (const float*)d_in[12];
  const float* attw_w  = (const float*)d_in[13];
  const float* attw_b  = (const float*)d_in[14];
  const float* mop_w   = (const float*)d_in[15];
  const float* mop_b   = (const float*)d_in[16];
  const float* dout_w  = (const float*)d_in[17];
  const float* dout_b  = (const float*)d_in[18];
  const float* ln3_g   = (const float*)d_in[19];
  const float* ln3_b   = (const float*)d_in[20];
  const float* geglu_w = (const float*)d_in[21];
  const float* geglu_b = (const float*)d_in[22];
  const float* dense_w = (const float*)d_in[23];
  const float* dense_b = (const float*)d_in[24];
  const float* pout_w  = (const float*)d_in[25];
  const float* pout_b  = (const float*)d_in[26];
  float* out = (float*)d_out;

  char* ws = (char*)d_ws;
  size_t off = 0;
  auto alloc = [&](size_t bytes) -> char* {
    off = (off + 255) & ~(size_t)255;
    char* p = ws + off;
    off += bytes;
    return p;
  };
  // persistent weights (bf16, transposed)
  bf16* wtPin   = (bf16*)alloc(512 * 512 * 2);
  bf16* wtVproj = (bf16*)alloc(512 * 512 * 2);
  bf16* wtMvp   = (bf16*)alloc(512 * 512 * 2);
  bf16* wtMop   = (bf16*)alloc(512 * 512 * 2);
  bf16* wtDout  = (bf16*)alloc(512 * 512 * 2);
  bf16* wtPout  = (bf16*)alloc(512 * 512 * 2);
  bf16* wtSoff  = (bf16*)alloc(128 * 512 * 2);
  bf16* wtAttw  = (bf16*)alloc(128 * 512 * 2);
  bf16* wtGeglu = (bf16*)alloc((size_t)4096 * 512 * 2);
  bf16* wtDense = (bf16*)alloc((size_t)512 * 2048 * 2);
  float* biasAttw = (float*)alloc(128 * 4);
  float* stats    = (float*)alloc(64 * 4);
  // activation regions with liveness-checked unions
  char* A = alloc(32 * MB);   // t32 (early) | hn @0 (16MB) + t3 @16MB
  char* Cg = alloc(32 * MB);  // t2 (fp32)
  char* D = alloc(64 * MB);   // xnt@0, v@16, v2@32, msda@48 | gpA@0 (64MB)
  char* E = alloc(64 * MB);   // q16@0, off@16(8), awl@24(8), m2@32(16) | ffin@0 (64MB)
  if (off > ws_size) return;  // workspace too small — fail loudly (zero output)

  float* t32   = (float*)A;
  bf16*  hn    = (bf16*)A;
  bf16*  t3    = (bf16*)(A + 16 * MB);
  float* t2    = (float*)Cg;
  bf16*  xnt   = (bf16*)D;
  bf16*  v16   = (bf16*)(D + 16 * MB);
  bf16*  v2b   = (bf16*)(D + 32 * MB);
  bf16*  msda  = (bf16*)(D + 48 * MB);
  bf16*  gpA   = (bf16*)D;
  bf16*  q16   = (bf16*)E;
  float* off32 = (float*)(E + 16 * MB);
  float* awl32 = (float*)(E + 24 * MB);
  bf16*  m2    = (bf16*)(E + 32 * MB);
  bf16*  ffin  = (bf16*)E;

  hipMemsetAsync(stats, 0, 64 * 4, stream);
  pad_bias64<<<1, 128, 0, stream>>>(attw_b, biasAttw);

  dim3 tb(32, 8);
  transpose_pad<<<dim3(16, 16),  tb, 0, stream>>>(pin_w,   wtPin,   512, 512, 512);
  transpose_pad<<<dim3(16, 16),  tb, 0, stream>>>(vproj_w, wtVproj, 512, 512, 512);
  transpose_pad<<<dim3(16, 16),  tb, 0, stream>>>(mvp_w,   wtMvp,   512, 512, 512);
  transpose_pad<<<dim3(16, 16),  tb, 0, stream>>>(mop_w,   wtMop,   512, 512, 512);
  transpose_pad<<<dim3(16, 16),  tb, 0, stream>>>(dout_w,  wtDout,  512, 512, 512);
  transpose_pad<<<dim3(16, 16),  tb, 0, stream>>>(pout_w,  wtPout,  512, 512, 512);
  transpose_pad<<<dim3(16, 4),   tb, 0, stream>>>(soff_w,  wtSoff,  512, 128, 128);
  transpose_pad<<<dim3(16, 4),   tb, 0, stream>>>(attw_w,  wtAttw,  512,  64, 128);
  transpose_pad<<<dim3(16, 128), tb, 0, stream>>>(geglu_w, wtGeglu, 512, 4096, 4096);
  transpose_pad<<<dim3(64, 16),  tb, 0, stream>>>(dense_w, wtDense, 2048, 512, 512);

  gn_partial<<<512, 256, 0, stream>>>(x, stats);
  gn_apply_t<<<dim3(128, 16, 4), tb, 0, stream>>>(x, stats, gn_g, gn_b, xnt);

  // t = xnt @ pin + b   (fp32 trunk)
  gemm_bt<float, float, 0><<<dim3(4, 128), 256, 0, stream>>>(
      xnt, wtPin, pin_b, nullptr, t32, M_, 512, 512);
  // q = LN1(t)  (bf16)
  layernorm_k<<<4096, 256, 0, stream>>>(t32, ln1_g, ln1_b, q16);
  // value = q @ vproj ; v2 = value @ mvp
  gemm_bt<bf16, float, 0><<<dim3(4, 128), 256, 0, stream>>>(
      q16, wtVproj, vproj_b, nullptr, v16, M_, 512, 512);
  gemm_bt<bf16, float, 0><<<dim3(4, 128), 256, 0, stream>>>(
      v16, wtMvp, mvp_b, nullptr, v2b, M_, 512, 512);
  // sampling offsets + attention logits (fp32 out)
  gemm_bt<float, float, 0><<<dim3(1, 128), 256, 0, stream>>>(
      q16, wtSoff, soff_b, nullptr, off32, M_, 128, 512);
  gemm_bt<float, float, 0><<<dim3(1, 128), 256, 0, stream>>>(
      q16, wtAttw, biasAttw, nullptr, awl32, M_, 128, 512);
  msda_k<<<32768, 256, 0, stream>>>(off32, awl32, v2b, msda);
  // m2 = msda @ mop + b + q ; t2 = m2 @ dout + b + t (fp32 trunk)
  gemm_bt<bf16, bf16, 1><<<dim3(4, 128), 256, 0, stream>>>(
      msda, wtMop, mop_b, q16, m2, M_, 512, 512);
  gemm_bt<float, float, 1><<<dim3(4, 128), 256, 0, stream>>>(
      m2, wtDout, dout_b, t32, t2, M_, 512, 512);
  // hn = LN3(t2)
  layernorm_k<<<4096, 256, 0, stream>>>(t2, ln3_g, ln3_b, hn);
  // GEGLU split: gpA = hn @ W[:, :2048] + b ; ffin = gpA * gelu(hn @ W[:, 2048:] + b)
  gemm_bt<bf16, float, 0><<<dim3(16, 128), 256, 0, stream>>>(
      hn, wtGeglu, geglu_b, nullptr, gpA, M_, 2048, 512);
  gemm_bt<bf16, bf16, 2><<<dim3(16, 128), 256, 0, stream>>>(
      hn, wtGeglu + (size_t)2048 * 512, geglu_b + 2048, gpA, ffin, M_, 2048, 512);
  // t3 = ffin @ dense + b + t2
  gemm_bt<bf16, float, 1><<<dim3(4, 128), 256, 0, stream>>>(
      ffin, wtDense, dense_b, t2, t3, M_, 512, 2048);
  // out[b,c,l] = (t3 @ pout + b)[b,l,c] + x[b,c,l]   (fused transpose epilogue)
  gemm_bt<float, float, 3><<<dim3(4, 128), 256, 0, stream>>>(
      t3, wtPout, pout_b, x, out, M_, 512, 512);
}